// Round 17
// baseline (890.652 us; speedup 1.0000x reference)
//
#include <hip/hip_runtime.h>

// B=4096, T=512, IN=32, H=[64,64,128], OUT=10
// 256 blocks x 512 threads (8 waves, 2/SIMD). ONE barrier/step, skewed pipeline:
//   iteration t: G01 (waves 0-3): layer0(t) + layer1(t-1)   [independent]
//                G23 (waves 4-7): layer2(t-2)
//                __syncthreads()
// R17: within-wave ILP merge — each role runs [all LDS reads][all MFMA][all trans]
// [all writes] so the 8 lstm_h chains interleave (trans is throughput-bound but the
// merged MFMA block now hides fully under the co-resident wave's trans section), and
// s_setprio(1) around G23's 48-MFMA cluster (T5: role-split waves -> arbitration
// favors the MFMA wave; trans cadence 1/16cyc leaves issue slots to spare).
// Race audit (h(t) stored in buffer t&1; pb=t&1, rb=pb^1):
//   l0 w:h0s[pb]=h0(t)    r:h0s[rb]=h0(t-1)                  (opposite buffer)
//   l1 w:h1s[rb]=h1(t-1)  r:h0s[rb]=h0(t-1), h1s[pb]=h1(t-2) (opp. buffer)
//   l2 w:h2s[pb]=h2(t-2)  r:h1s[pb]=h1(t-2) (prev iter, barrier-crossed),
//                         r:h2s[rb]=h2(t-3)                  (opposite buffer)
// Weights in AGPRs (PIN_A union AG[32]; R11): G01 28 slots (Wih0/Whh0/Wih1/Whh1),
// G23 32 (Whh2); Wih2 from LDS. 7-trans cell math (R15), pre-scaled biases (R12),
// native bf16 casts, builtin MFMAs only (compiler-managed hazards).

using f32x4  = __attribute__((ext_vector_type(4))) float;
using bf16x8 = __attribute__((ext_vector_type(8))) __bf16;

#define KS (-1.442695041f)   // -log2(e)
#define KT (-2.885390082f)   // -2*log2(e)

__device__ __forceinline__ float bf2f(__bf16 b) {
  unsigned short s = __builtin_bit_cast(unsigned short, b);
  unsigned u = ((unsigned)s) << 16;
  return __builtin_bit_cast(float, u);
}

// LSTM cell pointwise math, 7 trans ops (5 exp2 + 2 rcp).  bi*: PRE-SCALED biases.
__device__ __forceinline__ float lstm_h(float ai, float af, float ag, float ao,
                                        float bi0, float bi1, float bi2, float bi3,
                                        float& cs) {
  float Ei = __builtin_amdgcn_exp2f(fmaf(KS, ai, bi0));
  float Ef = __builtin_amdgcn_exp2f(fmaf(KS, af, bi1));
  float Eg = __builtin_amdgcn_exp2f(fmaf(KT, ag, bi2));
  float Eo = __builtin_amdgcn_exp2f(fmaf(KS, ao, bi3));
  float Pi = 1.0f + Ei, Pf = 1.0f + Ef, Pg = 1.0f + Eg, Po = 1.0f + Eo;
  float PiPg = Pi * Pg;
  float N    = fmaf(Pf, 1.0f - Eg, cs * PiPg);
  float nc   = N * __builtin_amdgcn_rcpf(Pf * PiPg);
  cs = nc;
  float En = __builtin_amdgcn_exp2f(KT * nc);
  return (1.0f - En) * __builtin_amdgcn_rcpf(fmaf(Po, En, Po));  // (1-En)/(Po(1+En))
}

#define MF(A, Bv, C) __builtin_amdgcn_mfma_f32_16x16x32_bf16((A), (Bv), (C), 0, 0, 0)
#define PIN_A(v) asm volatile("" : "+a"(v))

__device__ __forceinline__ bf16x8 ldw8(const float* p) {
  float4 v0 = *(const float4*)p;
  float4 v1 = *(const float4*)(p + 4);
  bf16x8 r;
  r[0] = (__bf16)v0.x; r[1] = (__bf16)v0.y; r[2] = (__bf16)v0.z; r[3] = (__bf16)v0.w;
  r[4] = (__bf16)v1.x; r[5] = (__bf16)v1.y; r[6] = (__bf16)v1.z; r[7] = (__bf16)v1.w;
  return r;
}

__global__ __launch_bounds__(512)
void lstm_kernel(const float* __restrict__ x,
                 const float* __restrict__ Wih0, const float* __restrict__ Whh0,
                 const float* __restrict__ bih0, const float* __restrict__ bhh0,
                 const float* __restrict__ Wih1, const float* __restrict__ Whh1,
                 const float* __restrict__ bih1, const float* __restrict__ bhh1,
                 const float* __restrict__ Wih2, const float* __restrict__ Whh2,
                 const float* __restrict__ bih2, const float* __restrict__ bhh2,
                 const float* __restrict__ Wfc, const float* __restrict__ bfc,
                 float* __restrict__ out) {
  __shared__ __align__(16) __bf16 h0s[2][16][72];
  __shared__ __align__(16) __bf16 h1s[2][16][72];
  __shared__ __align__(16) __bf16 h2s[2][16][136];
  __shared__ __align__(16) __bf16 wih2l[512][72];

  const int tid = threadIdx.x;
  const int w   = tid >> 6;      // wave 0..7
  const bool g01 = (w < 4);
  const int gw  = w & 3;
  const int l   = tid & 63;
  const int l15 = l & 15;
  const int lg  = l >> 4;
  const int k0  = lg * 8;
  const int r0  = blockIdx.x << 4;

  for (int i = tid; i < 2 * 16 * 72; i += 512) {
    (&h0s[0][0][0])[i] = __bf16(0.f);
    (&h1s[0][0][0])[i] = __bf16(0.f);
  }
  for (int i = tid; i < 2 * 16 * 136; i += 512) (&h2s[0][0][0])[i] = __bf16(0.f);
  for (int i = tid; i < 512 * 64; i += 512) {
    int row = i >> 6, col = i & 63;
    wih2l[row][col] = (__bf16)Wih2[i];
  }

  // ---- SHARED weight array (union across roles), pinned to AGPRs ----
  // G01: AG[0..3]=Wih0, AG[4..11]=Whh0, AG[12..19]=Wih1, AG[20..27]=Whh1
  // G23: AG[0..31]=Whh2 (s,gi,kk -> 16s+4gi+kk)
  bf16x8 AG[32];
#pragma unroll
  for (int i = 0; i < 32; ++i) AG[i] = bf16x8{};
  f32x4  AC[8];     // G01: AC[0..3]=l0, AC[4..7]=l1; G23: AC[0..3]=s0, AC[4..7]=s1
  float  BI[8];     // pre-scaled biases (gi==2 -> KT*b else KS*b)
  float  CS[8];     // cell states
#pragma unroll
  for (int i = 0; i < 8; ++i) CS[i] = 0.f;

  if (g01) {
#pragma unroll
    for (int gi = 0; gi < 4; ++gi) {
      const int row = 16 * (4 * gi + gw) + l15;
      AG[gi] = ldw8(Wih0 + (size_t)row * 32 + k0);
#pragma unroll
      for (int kb = 0; kb < 2; ++kb) {
        AG[4 + 2 * gi + kb]  = ldw8(Whh0 + (size_t)row * 64 + kb * 32 + k0);
        AG[12 + 2 * gi + kb] = ldw8(Wih1 + (size_t)row * 64 + kb * 32 + k0);
        AG[20 + 2 * gi + kb] = ldw8(Whh1 + (size_t)row * 64 + kb * 32 + k0);
      }
      const float sc = (gi == 2) ? KT : KS;
      const int c01 = 64 * gi + 16 * gw + l15;
      BI[gi]     = sc * (bih0[c01] + bhh0[c01]);
      BI[4 + gi] = sc * (bih1[c01] + bhh1[c01]);
    }
  } else {
#pragma unroll
    for (int s = 0; s < 2; ++s)
#pragma unroll
      for (int gi = 0; gi < 4; ++gi) {
        const int row = 16 * (8 * gi + 2 * gw + s) + l15;
#pragma unroll
        for (int kk = 0; kk < 4; ++kk)
          AG[16 * s + 4 * gi + kk] = ldw8(Whh2 + (size_t)row * 128 + kk * 32 + k0);
        const float sc = (gi == 2) ? KT : KS;
        const int c2 = 128 * gi + 32 * gw + 16 * s + l15;
        BI[4 * s + gi] = sc * (bih2[c2] + bhh2[c2]);
      }
  }
#pragma unroll
  for (int i = 0; i < 32; ++i) PIN_A(AG[i]);

  const float* xrow = x + (size_t)(r0 + l15) * 512 * 32 + k0;
  float4 nx0 = {0.f, 0.f, 0.f, 0.f}, nx1 = {0.f, 0.f, 0.f, 0.f};
  if (g01) { nx0 = *(const float4*)xrow; nx1 = *(const float4*)(xrow + 4); }

  const f32x4 Z0 = {0.f, 0.f, 0.f, 0.f};

  __syncthreads();

#pragma unroll 1
  for (int t = 0; t <= 513; ++t) {
    const int pb = t & 1, rb = pb ^ 1;

    if (g01) {
      if (t <= 512) {
        // ---- all LDS reads first ----
        bf16x8 a0 = *(const bf16x8*)&h0s[rb][l15][k0];        // h0(t-1)
        bf16x8 a1 = *(const bf16x8*)&h0s[rb][l15][32 + k0];
        bf16x8 b0, b1;
        if (t >= 1) {
          b0 = *(const bf16x8*)&h1s[pb][l15][k0];             // h1(t-2)
          b1 = *(const bf16x8*)&h1s[pb][l15][32 + k0];
        }

        // ---- l0(t) MFMA (AC[0..3]) ----
        bf16x8 ax;
        if (t < 512) {
          float4 cx0 = nx0, cx1 = nx1;
          const int tn = (t + 1) & 511;  // wraparound dummy at t=511
          nx0 = *(const float4*)(xrow + (size_t)tn * 32);
          nx1 = *(const float4*)(xrow + (size_t)tn * 32 + 4);
          ax[0] = (__bf16)cx0.x; ax[1] = (__bf16)cx0.y; ax[2] = (__bf16)cx0.z; ax[3] = (__bf16)cx0.w;
          ax[4] = (__bf16)cx1.x; ax[5] = (__bf16)cx1.y; ax[6] = (__bf16)cx1.z; ax[7] = (__bf16)cx1.w;
#pragma unroll
          for (int gi = 0; gi < 4; ++gi) {
            f32x4 a = Z0;
            a = MF(ax, AG[gi], a);
            a = MF(a0, AG[4 + 2 * gi], a);
            a = MF(a1, AG[5 + 2 * gi], a);
            AC[gi] = a;
          }
        }

        // ---- l1(t-1) MFMA (AC[4..7]) ----
        if (t >= 1) {
#pragma unroll
          for (int gi = 0; gi < 4; ++gi) {
            f32x4 a = Z0;
            a = MF(a0, AG[12 + 2 * gi], a);
            a = MF(a1, AG[13 + 2 * gi], a);
            a = MF(b0, AG[20 + 2 * gi], a);
            a = MF(b1, AG[21 + 2 * gi], a);
            AC[4 + gi] = a;
          }
        }

        // ---- all trans + writes (8 independent lstm_h chains) ----
        if (t < 512) {
#pragma unroll
          for (int j = 0; j < 4; ++j) {
            float h = lstm_h(AC[0][j], AC[1][j], AC[2][j], AC[3][j],
                             BI[0], BI[1], BI[2], BI[3], CS[j]);
            h0s[pb][4 * lg + j][16 * gw + l15] = (__bf16)h;
          }
        }
        if (t >= 1) {
#pragma unroll
          for (int j = 0; j < 4; ++j) {
            float h = lstm_h(AC[4][j], AC[5][j], AC[6][j], AC[7][j],
                             BI[4], BI[5], BI[6], BI[7], CS[4 + j]);
            h1s[rb][4 * lg + j][16 * gw + l15] = (__bf16)h;
          }
        }
      }
    } else {
      if (t >= 2) {
        // -------- layer2(t-2): h2(t-2) = cell(h1(t-2), h2(t-3)) --------
        bf16x8 b0 = *(const bf16x8*)&h1s[pb][l15][k0];
        bf16x8 b1 = *(const bf16x8*)&h1s[pb][l15][32 + k0];
        bf16x8 d0 = *(const bf16x8*)&h2s[rb][l15][k0];
        bf16x8 d1 = *(const bf16x8*)&h2s[rb][l15][32 + k0];
        bf16x8 d2 = *(const bf16x8*)&h2s[rb][l15][64 + k0];
        bf16x8 d3 = *(const bf16x8*)&h2s[rb][l15][96 + k0];

        __builtin_amdgcn_s_setprio(1);
        // s=0 MFMA (AC[0..3])
#pragma unroll
        for (int gi = 0; gi < 4; ++gi) {
          const int tile = 8 * gi + 2 * gw;
          bf16x8 wa0 = *(const bf16x8*)&wih2l[16 * tile + l15][k0];
          bf16x8 wa1 = *(const bf16x8*)&wih2l[16 * tile + l15][32 + k0];
          f32x4 a = Z0;
          a = MF(b0, wa0, a);
          a = MF(b1, wa1, a);
          a = MF(d0, AG[4 * gi + 0], a);
          a = MF(d1, AG[4 * gi + 1], a);
          a = MF(d2, AG[4 * gi + 2], a);
          a = MF(d3, AG[4 * gi + 3], a);
          AC[gi] = a;
        }
        // s=1 MFMA (AC[4..7])
#pragma unroll
        for (int gi = 0; gi < 4; ++gi) {
          const int tile = 8 * gi + 2 * gw + 1;
          bf16x8 wa0 = *(const bf16x8*)&wih2l[16 * tile + l15][k0];
          bf16x8 wa1 = *(const bf16x8*)&wih2l[16 * tile + l15][32 + k0];
          f32x4 a = Z0;
          a = MF(b0, wa0, a);
          a = MF(b1, wa1, a);
          a = MF(d0, AG[16 + 4 * gi + 0], a);
          a = MF(d1, AG[16 + 4 * gi + 1], a);
          a = MF(d2, AG[16 + 4 * gi + 2], a);
          a = MF(d3, AG[16 + 4 * gi + 3], a);
          AC[4 + gi] = a;
        }
        __builtin_amdgcn_s_setprio(0);

        // all trans + writes (8 independent lstm_h chains)
#pragma unroll
        for (int j = 0; j < 4; ++j) {
          float h = lstm_h(AC[0][j], AC[1][j], AC[2][j], AC[3][j],
                           BI[0], BI[1], BI[2], BI[3], CS[j]);
          h2s[pb][4 * lg + j][32 * gw + l15] = (__bf16)h;
        }
#pragma unroll
        for (int j = 0; j < 4; ++j) {
          float h = lstm_h(AC[4][j], AC[5][j], AC[6][j], AC[7][j],
                           BI[4], BI[5], BI[6], BI[7], CS[4 + j]);
          h2s[pb][4 * lg + j][32 * gw + 16 + l15] = (__bf16)h;
        }
      }
    }
    __syncthreads();  // single barrier per step
  }

  // ---- final FC: out = h2(511) @ Wfc^T + bfc;  h2(511) written at t=513 -> h2s[1]
  if (tid < 160) {
    const int r = tid / 10, o = tid - r * 10;
    float sum = bfc[o];
    for (int u = 0; u < 128; ++u) sum += bf2f(h2s[1][r][u]) * Wfc[o * 128 + u];
    out[(size_t)(r0 + r) * 10 + o] = sum;
  }
}

extern "C" void kernel_launch(void* const* d_in, const int* in_sizes, int n_in,
                              void* d_out, int out_size, void* d_ws, size_t ws_size,
                              hipStream_t stream) {
  const float* x    = (const float*)d_in[0];
  const float* Wih0 = (const float*)d_in[1];
  const float* Whh0 = (const float*)d_in[2];
  const float* bih0 = (const float*)d_in[3];
  const float* bhh0 = (const float*)d_in[4];
  const float* Wih1 = (const float*)d_in[5];
  const float* Whh1 = (const float*)d_in[6];
  const float* bih1 = (const float*)d_in[7];
  const float* bhh1 = (const float*)d_in[8];
  const float* Wih2 = (const float*)d_in[9];
  const float* Whh2 = (const float*)d_in[10];
  const float* bih2 = (const float*)d_in[11];
  const float* bhh2 = (const float*)d_in[12];
  const float* Wfc  = (const float*)d_in[13];
  const float* bfc  = (const float*)d_in[14];

  lstm_kernel<<<256, 512, 0, stream>>>(x, Wih0, Whh0, bih0, bhh0,
                                       Wih1, Whh1, bih1, bhh1,
                                       Wih2, Whh2, bih2, bhh2,
                                       Wfc, bfc, (float*)d_out);
}

// Round 18
// 850.388 us; speedup vs baseline: 1.0473x; 1.0473x over previous
//
#include <hip/hip_runtime.h>

// B=4096, T=512, IN=32, H=[64,64,128], OUT=10
// 256 blocks x 512 threads (8 waves, 2/SIMD). ONE barrier/step via pipeline skew:
//   iteration t: G01 (waves 0-3): layer0(t) ; layer1(t-1)   [independent chains]
//                G23 (waves 4-7): layer2(t-2)
//                __syncthreads()
// == R16 exactly (best measured: 855 us). R17's phase-merge + setprio regressed
// (setprio boosts G23-MFMA at the expense of G01's scarce VALU/trans stream).
// Race audit (h(t) stored in buffer t&1; pb=t&1, rb=pb^1):
//   l0 w:h0s[pb]=h0(t)    r:h0s[rb]=h0(t-1)                  (opposite buffer)
//   l1 w:h1s[rb]=h1(t-1)  r:h0s[rb]=h0(t-1) (same data l0 reads -> frag reuse),
//                         r:h1s[pb]=h1(t-2)                  (opposite buffer)
//   l2 w:h2s[pb]=h2(t-2)  r:h1s[pb]=h1(t-2) (prev iter, barrier-crossed),
//                         r:h2s[rb]=h2(t-3)                  (opposite buffer)
// Weights in AGPRs (PIN_A union AG[32] = 128 AGPR/wave): G01 28 slots
// (Wih0/Whh0/Wih1/Whh1), G23 32 (Whh2); Wih2 from LDS (padded rows, 2-way only).
// 7-trans cell math (R15), pre-scaled biases (R12), native bf16 casts, builtin MFMAs.

using f32x4  = __attribute__((ext_vector_type(4))) float;
using bf16x8 = __attribute__((ext_vector_type(8))) __bf16;

#define KS (-1.442695041f)   // -log2(e)
#define KT (-2.885390082f)   // -2*log2(e)

__device__ __forceinline__ float bf2f(__bf16 b) {
  unsigned short s = __builtin_bit_cast(unsigned short, b);
  unsigned u = ((unsigned)s) << 16;
  return __builtin_bit_cast(float, u);
}

// LSTM cell pointwise math, 7 trans ops (5 exp2 + 2 rcp).  bi*: PRE-SCALED biases.
__device__ __forceinline__ float lstm_h(float ai, float af, float ag, float ao,
                                        float bi0, float bi1, float bi2, float bi3,
                                        float& cs) {
  float Ei = __builtin_amdgcn_exp2f(fmaf(KS, ai, bi0));
  float Ef = __builtin_amdgcn_exp2f(fmaf(KS, af, bi1));
  float Eg = __builtin_amdgcn_exp2f(fmaf(KT, ag, bi2));
  float Eo = __builtin_amdgcn_exp2f(fmaf(KS, ao, bi3));
  float Pi = 1.0f + Ei, Pf = 1.0f + Ef, Pg = 1.0f + Eg, Po = 1.0f + Eo;
  float PiPg = Pi * Pg;
  float N    = fmaf(Pf, 1.0f - Eg, cs * PiPg);
  float nc   = N * __builtin_amdgcn_rcpf(Pf * PiPg);
  cs = nc;
  float En = __builtin_amdgcn_exp2f(KT * nc);
  return (1.0f - En) * __builtin_amdgcn_rcpf(fmaf(Po, En, Po));  // (1-En)/(Po(1+En))
}

#define MF(A, Bv, C) __builtin_amdgcn_mfma_f32_16x16x32_bf16((A), (Bv), (C), 0, 0, 0)
#define PIN_A(v) asm volatile("" : "+a"(v))

__device__ __forceinline__ bf16x8 ldw8(const float* p) {
  float4 v0 = *(const float4*)p;
  float4 v1 = *(const float4*)(p + 4);
  bf16x8 r;
  r[0] = (__bf16)v0.x; r[1] = (__bf16)v0.y; r[2] = (__bf16)v0.z; r[3] = (__bf16)v0.w;
  r[4] = (__bf16)v1.x; r[5] = (__bf16)v1.y; r[6] = (__bf16)v1.z; r[7] = (__bf16)v1.w;
  return r;
}

__global__ __launch_bounds__(512)
void lstm_kernel(const float* __restrict__ x,
                 const float* __restrict__ Wih0, const float* __restrict__ Whh0,
                 const float* __restrict__ bih0, const float* __restrict__ bhh0,
                 const float* __restrict__ Wih1, const float* __restrict__ Whh1,
                 const float* __restrict__ bih1, const float* __restrict__ bhh1,
                 const float* __restrict__ Wih2, const float* __restrict__ Whh2,
                 const float* __restrict__ bih2, const float* __restrict__ bhh2,
                 const float* __restrict__ Wfc, const float* __restrict__ bfc,
                 float* __restrict__ out) {
  __shared__ __align__(16) __bf16 h0s[2][16][72];
  __shared__ __align__(16) __bf16 h1s[2][16][72];
  __shared__ __align__(16) __bf16 h2s[2][16][136];
  __shared__ __align__(16) __bf16 wih2l[512][72];

  const int tid = threadIdx.x;
  const int w   = tid >> 6;      // wave 0..7
  const bool g01 = (w < 4);
  const int gw  = w & 3;
  const int l   = tid & 63;
  const int l15 = l & 15;
  const int lg  = l >> 4;
  const int k0  = lg * 8;
  const int r0  = blockIdx.x << 4;

  for (int i = tid; i < 2 * 16 * 72; i += 512) {
    (&h0s[0][0][0])[i] = __bf16(0.f);
    (&h1s[0][0][0])[i] = __bf16(0.f);
  }
  for (int i = tid; i < 2 * 16 * 136; i += 512) (&h2s[0][0][0])[i] = __bf16(0.f);
  for (int i = tid; i < 512 * 64; i += 512) {
    int row = i >> 6, col = i & 63;
    wih2l[row][col] = (__bf16)Wih2[i];
  }

  // ---- SHARED weight array (union across roles), pinned to AGPRs ----
  // G01: AG[0..3]=Wih0, AG[4..11]=Whh0, AG[12..19]=Wih1, AG[20..27]=Whh1
  // G23: AG[0..31]=Whh2 (s,gi,kk -> 16s+4gi+kk)
  bf16x8 AG[32];
#pragma unroll
  for (int i = 0; i < 32; ++i) AG[i] = bf16x8{};
  f32x4  AC[8];     // G01: AC[0..3]=l0, AC[4..7]=l1; G23: AC[0..3]=s0, AC[4..7]=s1
  float  BI[8];     // pre-scaled biases (gi==2 -> KT*b else KS*b)
  float  CS[8];     // cell states
#pragma unroll
  for (int i = 0; i < 8; ++i) CS[i] = 0.f;

  if (g01) {
#pragma unroll
    for (int gi = 0; gi < 4; ++gi) {
      const int row = 16 * (4 * gi + gw) + l15;
      AG[gi] = ldw8(Wih0 + (size_t)row * 32 + k0);
#pragma unroll
      for (int kb = 0; kb < 2; ++kb) {
        AG[4 + 2 * gi + kb]  = ldw8(Whh0 + (size_t)row * 64 + kb * 32 + k0);
        AG[12 + 2 * gi + kb] = ldw8(Wih1 + (size_t)row * 64 + kb * 32 + k0);
        AG[20 + 2 * gi + kb] = ldw8(Whh1 + (size_t)row * 64 + kb * 32 + k0);
      }
      const float sc = (gi == 2) ? KT : KS;
      const int c01 = 64 * gi + 16 * gw + l15;
      BI[gi]     = sc * (bih0[c01] + bhh0[c01]);
      BI[4 + gi] = sc * (bih1[c01] + bhh1[c01]);
    }
  } else {
#pragma unroll
    for (int s = 0; s < 2; ++s)
#pragma unroll
      for (int gi = 0; gi < 4; ++gi) {
        const int row = 16 * (8 * gi + 2 * gw + s) + l15;
#pragma unroll
        for (int kk = 0; kk < 4; ++kk)
          AG[16 * s + 4 * gi + kk] = ldw8(Whh2 + (size_t)row * 128 + kk * 32 + k0);
        const float sc = (gi == 2) ? KT : KS;
        const int c2 = 128 * gi + 32 * gw + 16 * s + l15;
        BI[4 * s + gi] = sc * (bih2[c2] + bhh2[c2]);
      }
  }
#pragma unroll
  for (int i = 0; i < 32; ++i) PIN_A(AG[i]);

  const float* xrow = x + (size_t)(r0 + l15) * 512 * 32 + k0;
  float4 nx0 = {0.f, 0.f, 0.f, 0.f}, nx1 = {0.f, 0.f, 0.f, 0.f};
  if (g01) { nx0 = *(const float4*)xrow; nx1 = *(const float4*)(xrow + 4); }

  const f32x4 Z0 = {0.f, 0.f, 0.f, 0.f};

  __syncthreads();

#pragma unroll 1
  for (int t = 0; t <= 513; ++t) {
    const int pb = t & 1, rb = pb ^ 1;

    if (g01) {
      if (t <= 512) {
        // h0(t-1) fragments — shared input of l0(t) and l1(t-1)
        bf16x8 a0 = *(const bf16x8*)&h0s[rb][l15][k0];
        bf16x8 a1 = *(const bf16x8*)&h0s[rb][l15][32 + k0];

        if (t < 512) {
          // -------- layer0(t): h0(t) = cell(x(t), h0(t-1)) --------
          float4 cx0 = nx0, cx1 = nx1;
          const int tn = (t + 1) & 511;  // wraparound dummy at t=511
          nx0 = *(const float4*)(xrow + (size_t)tn * 32);
          nx1 = *(const float4*)(xrow + (size_t)tn * 32 + 4);

          bf16x8 ax;
          ax[0] = (__bf16)cx0.x; ax[1] = (__bf16)cx0.y; ax[2] = (__bf16)cx0.z; ax[3] = (__bf16)cx0.w;
          ax[4] = (__bf16)cx1.x; ax[5] = (__bf16)cx1.y; ax[6] = (__bf16)cx1.z; ax[7] = (__bf16)cx1.w;
#pragma unroll
          for (int gi = 0; gi < 4; ++gi) {
            f32x4 a = Z0;
            a = MF(ax, AG[gi], a);
            a = MF(a0, AG[4 + 2 * gi], a);
            a = MF(a1, AG[5 + 2 * gi], a);
            AC[gi] = a;
          }
#pragma unroll
          for (int j = 0; j < 4; ++j) {
            float h = lstm_h(AC[0][j], AC[1][j], AC[2][j], AC[3][j],
                             BI[0], BI[1], BI[2], BI[3], CS[j]);
            h0s[pb][4 * lg + j][16 * gw + l15] = (__bf16)h;
          }
        }

        if (t >= 1) {
          // -------- layer1(t-1): h1(t-1) = cell(h0(t-1), h1(t-2)) --------
          bf16x8 b0 = *(const bf16x8*)&h1s[pb][l15][k0];
          bf16x8 b1 = *(const bf16x8*)&h1s[pb][l15][32 + k0];
#pragma unroll
          for (int gi = 0; gi < 4; ++gi) {
            f32x4 a = Z0;
            a = MF(a0, AG[12 + 2 * gi], a);
            a = MF(a1, AG[13 + 2 * gi], a);
            a = MF(b0, AG[20 + 2 * gi], a);
            a = MF(b1, AG[21 + 2 * gi], a);
            AC[4 + gi] = a;
          }
#pragma unroll
          for (int j = 0; j < 4; ++j) {
            float h = lstm_h(AC[4][j], AC[5][j], AC[6][j], AC[7][j],
                             BI[4], BI[5], BI[6], BI[7], CS[4 + j]);
            h1s[rb][4 * lg + j][16 * gw + l15] = (__bf16)h;
          }
        }
      }
    } else {
      if (t >= 2) {
        // -------- layer2(t-2): h2(t-2) = cell(h1(t-2), h2(t-3)) --------
        bf16x8 b0 = *(const bf16x8*)&h1s[pb][l15][k0];
        bf16x8 b1 = *(const bf16x8*)&h1s[pb][l15][32 + k0];
        bf16x8 d0 = *(const bf16x8*)&h2s[rb][l15][k0];
        bf16x8 d1 = *(const bf16x8*)&h2s[rb][l15][32 + k0];
        bf16x8 d2 = *(const bf16x8*)&h2s[rb][l15][64 + k0];
        bf16x8 d3 = *(const bf16x8*)&h2s[rb][l15][96 + k0];
        // s = 0
#pragma unroll
        for (int gi = 0; gi < 4; ++gi) {
          const int tile = 8 * gi + 2 * gw;
          bf16x8 wa0 = *(const bf16x8*)&wih2l[16 * tile + l15][k0];
          bf16x8 wa1 = *(const bf16x8*)&wih2l[16 * tile + l15][32 + k0];
          f32x4 a = Z0;
          a = MF(b0, wa0, a);
          a = MF(b1, wa1, a);
          a = MF(d0, AG[4 * gi + 0], a);
          a = MF(d1, AG[4 * gi + 1], a);
          a = MF(d2, AG[4 * gi + 2], a);
          a = MF(d3, AG[4 * gi + 3], a);
          AC[gi] = a;
        }
#pragma unroll
        for (int j = 0; j < 4; ++j) {
          float h = lstm_h(AC[0][j], AC[1][j], AC[2][j], AC[3][j],
                           BI[0], BI[1], BI[2], BI[3], CS[j]);
          h2s[pb][4 * lg + j][32 * gw + l15] = (__bf16)h;
        }
        // s = 1
#pragma unroll
        for (int gi = 0; gi < 4; ++gi) {
          const int tile = 8 * gi + 2 * gw + 1;
          bf16x8 wa0 = *(const bf16x8*)&wih2l[16 * tile + l15][k0];
          bf16x8 wa1 = *(const bf16x8*)&wih2l[16 * tile + l15][32 + k0];
          f32x4 a = Z0;
          a = MF(b0, wa0, a);
          a = MF(b1, wa1, a);
          a = MF(d0, AG[16 + 4 * gi + 0], a);
          a = MF(d1, AG[16 + 4 * gi + 1], a);
          a = MF(d2, AG[16 + 4 * gi + 2], a);
          a = MF(d3, AG[16 + 4 * gi + 3], a);
          AC[4 + gi] = a;
        }
#pragma unroll
        for (int j = 0; j < 4; ++j) {
          float h = lstm_h(AC[4][j], AC[5][j], AC[6][j], AC[7][j],
                           BI[4], BI[5], BI[6], BI[7], CS[4 + j]);
          h2s[pb][4 * lg + j][32 * gw + 16 + l15] = (__bf16)h;
        }
      }
    }
    __syncthreads();  // single barrier per step
  }

  // ---- final FC: out = h2(511) @ Wfc^T + bfc;  h2(511) written at t=513 -> h2s[1]
  if (tid < 160) {
    const int r = tid / 10, o = tid - r * 10;
    float sum = bfc[o];
    for (int u = 0; u < 128; ++u) sum += bf2f(h2s[1][r][u]) * Wfc[o * 128 + u];
    out[(size_t)(r0 + r) * 10 + o] = sum;
  }
}

extern "C" void kernel_launch(void* const* d_in, const int* in_sizes, int n_in,
                              void* d_out, int out_size, void* d_ws, size_t ws_size,
                              hipStream_t stream) {
  const float* x    = (const float*)d_in[0];
  const float* Wih0 = (const float*)d_in[1];
  const float* Whh0 = (const float*)d_in[2];
  const float* bih0 = (const float*)d_in[3];
  const float* bhh0 = (const float*)d_in[4];
  const float* Wih1 = (const float*)d_in[5];
  const float* Whh1 = (const float*)d_in[6];
  const float* bih1 = (const float*)d_in[7];
  const float* bhh1 = (const float*)d_in[8];
  const float* Wih2 = (const float*)d_in[9];
  const float* Whh2 = (const float*)d_in[10];
  const float* bih2 = (const float*)d_in[11];
  const float* bhh2 = (const float*)d_in[12];
  const float* Wfc  = (const float*)d_in[13];
  const float* bfc  = (const float*)d_in[14];

  lstm_kernel<<<256, 512, 0, stream>>>(x, Wih0, Whh0, bih0, bhh0,
                                       Wih1, Whh1, bih1, bhh1,
                                       Wih2, Whh2, bih2, bhh2,
                                       Wfc, bfc, (float*)d_out);
}